// Round 9
// baseline (98.320 us; speedup 1.0000x reference)
//
#include <hip/hip_runtime.h>

#define NROWS 8192
#define DIMX  128            // raw feature dims
#define K2    144            // padded K: 128 data + 1 sq-dim + 10 one-hot + 5 zero (9 x K16)
#define KSEG  18             // 16B segments per row (288 B)
#define NKS   9              // MFMA K-steps (32x32x16)
#define PTS   18432          // shorts per 128-row panel tile (128*144)
#define NCLS  10
#define GAPV  0.4f
#define BIAS  2048.0f        // 2 * 32 * 32
#define C0    128.0f         // sq centering constant
#define RGR   256            // rows per block (4 waves x 64 rows)
#define NRG   (NROWS / RGR)        // 32 rowgroups
#define CHUNK 512            // cols per block
#define NCHUNK (NROWS / CHUNK)     // 16 col-chunks
#define SLAB  64             // cols per LDS slab
#define NSLAB (CHUNK / SLAB)       // 8 slabs

typedef __attribute__((ext_vector_type(8))) short bf16x8;
typedef __attribute__((ext_vector_type(16))) float f32x16;

// async 16B/lane global->LDS DMA
#define GLOAD_LDS16(g, l)                                              \
  __builtin_amdgcn_global_load_lds(                                    \
      (const __attribute__((address_space(1))) void*)(g),              \
      (__attribute__((address_space(3))) void*)(l), 16, 0, 0)

// monotone float <-> uint encoding so atomicMax/atomicMin on uint order like floats
__device__ __forceinline__ unsigned fenc(float f) {
  unsigned u = __float_as_uint(f);
  return (u & 0x80000000u) ? ~u : (u | 0x80000000u);
}
__device__ __forceinline__ float fdec(unsigned u) {
  return (u & 0x80000000u) ? __uint_as_float(u & 0x7fffffffu) : __uint_as_float(~u);
}
__device__ __forceinline__ short f2bf(float f) {  // RNE fp32->bf16
  unsigned u = __float_as_uint(f);
  u += 0x7fffu + ((u >> 16) & 1u);
  return (short)(u >> 16);
}

// ---- kernel 1: build augmented bf16 PANEL arrays (K2=144), sq, init, confusion, ctrs ----
// panel short addr = (row>>7)*PTS + kseg*1024 + (row&127)*8 + w8   (kseg 0..17)
// row: [bf16(x[0..127]), (A:1.0|B:-(s-128)/2), +/-32*onehot(cls), 0x5]
__global__ __launch_bounds__(256) void prep_k(const float* __restrict__ x,
                                              const int* __restrict__ tgt,
                                              const float* __restrict__ pred,
                                              short* __restrict__ xa,
                                              short* __restrict__ xbm,
                                              float* __restrict__ sq,
                                              unsigned* __restrict__ emax,
                                              unsigned* __restrict__ emin,
                                              int* __restrict__ conf,
                                              unsigned* __restrict__ ctrs) {
  if (blockIdx.x == 0 && threadIdx.x < NRG + 3) ctrs[threadIdx.x] = 0u;

  const int wave = threadIdx.x >> 6;
  const int lane = threadIdx.x & 63;
  const int row  = blockIdx.x * 4 + wave;
  const float2 f2 = ((const float2*)(x + (size_t)row * DIMX))[lane];
  float s = f2.x * f2.x + f2.y * f2.y;
  #pragma unroll
  for (int m = 1; m < 64; m <<= 1) s += __shfl_xor(s, m, 64);

  const size_t base = (size_t)(row >> 7) * PTS + (size_t)(row & 127) * 8;
  {  // data elems 2L, 2L+1 -> kseg = L>>2, short pair (L&3)*2
    const unsigned lo = (unsigned short)f2bf(f2.x);
    const unsigned hi = (unsigned short)f2bf(f2.y);
    const unsigned u  = lo | (hi << 16);
    const size_t off = base + (size_t)(lane >> 2) * 1024 + (lane & 3) * 2;
    *(unsigned*)(xa + off)  = u;
    *(unsigned*)(xbm + off) = u;
  }
  const int cls = tgt[row];
  if (lane < 8) {  // aug elems si = 128+2m, 129+2m (m=lane), ksegs 16..17
    const int m = lane;
    const int si0 = 128 + 2 * m, si1 = si0 + 1;
    unsigned a0 = 0, a1 = 0, b0 = 0, b1 = 0;
    if (si0 == 128) { a0 = 0x3F80u; b0 = (unsigned short)f2bf(-0.5f * (s - C0)); }
    else if (si0 <= 138 && cls == si0 - 129) { a0 = 0x4200u; b0 = 0xC200u; }
    if (si1 <= 138 && cls == si1 - 129) { a1 = 0x4200u; b1 = 0xC200u; }
    const size_t off = base + (size_t)(16 + (m >> 2)) * 1024 + ((2 * m) & 7);
    *(unsigned*)(xa + off)  = a0 | (a1 << 16);
    *(unsigned*)(xbm + off) = b0 | (b1 << 16);
  }

  if (lane == 0) {
    sq[row]   = s;
    emax[row] = fenc(-INFINITY);
    emin[row] = fenc(INFINITY);
    const float* pp = pred + (size_t)row * NCLS;
    float v[NCLS];
    #pragma unroll
    for (int c = 0; c < NCLS; ++c) v[c] = pp[c];
    float m1 = v[0]; int i1 = 0;
    #pragma unroll
    for (int c = 1; c < NCLS; ++c)
      if (v[c] > m1) { m1 = v[c]; i1 = c; }
    float m2 = -INFINITY, sum = 0.f;
    #pragma unroll
    for (int c = 0; c < NCLS; ++c) {
      sum += __expf(v[c] - m1);
      if (c != i1) m2 = fmaxf(m2, v[c]);
    }
    const float d01 = (1.f - __expf(m2 - m1)) / sum;
    conf[row] = (d01 <= GAPV) || (i1 != cls);
  }
}

// ---- kernel 2: Gram + hard mining, 32x32x16 MFMA, DMA-staged B, fused finalize ----
// 4 waves/block x 64 rows (2 x 32-row tiles, A register-resident). B: 512-col chunk
// in 8 x 64-col slabs via global_load_lds, double-buffered 2-barrier loop.
// A/B frag: m|n = lane&31, k = (lane>>5)*8 + e.  C/D: col=lane&31,
// row=(reg&3)+8*(reg>>2)+4*(lane>>5)  [verified m74/m101].
__global__ __launch_bounds__(256, 2) void gram_k(const short* __restrict__ xa,
                                                 const short* __restrict__ xbm,
                                                 const float* __restrict__ sq,
                                                 const int* __restrict__ conf,
                                                 unsigned* __restrict__ emax,
                                                 unsigned* __restrict__ emin,
                                                 unsigned* __restrict__ ctrs,
                                                 float* __restrict__ out) {
  __shared__ short lds[2][KSEG * 512];   // per buf: 18 ksegs x 64 cols x 16B = 18 KB
  __shared__ float red[2][4];
  __shared__ int   flag;
  const int tid  = threadIdx.x;
  const int wave = tid >> 6;
  const int lane = tid & 63;
  const int c31  = lane & 31;
  const int h    = lane >> 5;     // k-half
  const int bx = blockIdx.x, by = blockIdx.y;
  const int i0 = bx * RGR + wave * 64;

  unsigned* rg_done = ctrs;                 // [NRG]
  unsigned* g_done  = ctrs + NRG;
  float*    Ssum    = (float*)(ctrs + NRG + 1);
  float*    Csum    = (float*)(ctrs + NRG + 2);

  // A fragments: rows i0 + rt*32 + c31, kseg = 2*ks + h  (72 VGPRs)
  bf16x8 A[2][NKS];
  #pragma unroll
  for (int rt = 0; rt < 2; ++rt) {
    const int rbase = wave * 64 + rt * 32;               // 0..224 within 256-row block
    const short* pa = xa + (size_t)(bx * 2 + (rbase >> 7)) * PTS
                         + (size_t)((rbase & 127) + c31) * 8 + (size_t)h * 1024;
    #pragma unroll
    for (int ks = 0; ks < NKS; ++ks)
      A[rt][ks] = *(const bf16x8*)(pa + (size_t)ks * 2048);
  }
  #pragma unroll
  for (int rt = 0; rt < 2; ++rt)
    #pragma unroll
    for (int ks = 0; ks < NKS; ++ks)
      asm("" : "+v"(A[rt][ks]));   // keep A resident

  float gmin[2][16], gmax[2][16];
  #pragma unroll
  for (int rt = 0; rt < 2; ++rt)
    #pragma unroll
    for (int e = 0; e < 16; ++e) { gmin[rt][e] = INFINITY; gmax[rt][e] = -INFINITY; }

  // DMA slab 0: wave w stages ksegs w*4..w*4+3, waves 0/1 also 16/17
  {
    const short* srcb = xbm + (size_t)(by * 4) * PTS;
    #pragma unroll
    for (int u = 0; u < 4; ++u) {
      const int kseg = wave * 4 + u;
      GLOAD_LDS16(srcb + (size_t)kseg * 1024 + lane * 8, &lds[0][kseg * 512 + lane * 8]);
    }
    if (wave < 2) {
      const int kseg = 16 + wave;
      GLOAD_LDS16(srcb + (size_t)kseg * 1024 + lane * 8, &lds[0][kseg * 512 + lane * 8]);
    }
  }

  for (int s = 0; s < NSLAB; ++s) {
    __syncthreads();   // drains this wave's DMA + syncs buf ready
    if (s + 1 < NSLAB) {
      const short* srcb = xbm + (size_t)(by * 4 + ((s + 1) >> 1)) * PTS + ((s + 1) & 1) * 512;
      short* dstb = &lds[(s + 1) & 1][0];
      #pragma unroll
      for (int u = 0; u < 4; ++u) {
        const int kseg = wave * 4 + u;
        GLOAD_LDS16(srcb + (size_t)kseg * 1024 + lane * 8, dstb + kseg * 512 + lane * 8);
      }
      if (wave < 2) {
        const int kseg = 16 + wave;
        GLOAD_LDS16(srcb + (size_t)kseg * 1024 + lane * 8, dstb + kseg * 512 + lane * 8);
      }
    }
    // compute slab s: 2 col-tiles of 32
    const short* buf = lds[s & 1];
    #pragma unroll
    for (int ct = 0; ct < 2; ++ct) {
      bf16x8 B[NKS];
      #pragma unroll
      for (int ks = 0; ks < NKS; ++ks)
        B[ks] = *(const bf16x8*)(buf + (2 * ks + h) * 512 + (ct * 32 + c31) * 8);

      f32x16 acc[2];
      #pragma unroll
      for (int rt = 0; rt < 2; ++rt)
        #pragma unroll
        for (int e = 0; e < 16; ++e) acc[rt][e] = 0.f;
      #pragma unroll
      for (int ks = 0; ks < NKS; ++ks)
        #pragma unroll
        for (int rt = 0; rt < 2; ++rt)
          acc[rt] = __builtin_amdgcn_mfma_f32_32x32x16_bf16(A[rt][ks], B[ks], acc[rt], 0, 0, 0);

      #pragma unroll
      for (int rt = 0; rt < 2; ++rt)
        #pragma unroll
        for (int e = 0; e < 16; ++e) {
          gmin[rt][e] = fminf(gmin[rt][e], acc[rt][e]);
          gmax[rt][e] = fmaxf(gmax[rt][e], acc[rt][e]);
        }
    }
  }

  // reduce over the 32 cols held across c31 lanes (k-half bit preserved)
  #pragma unroll
  for (int m = 1; m <= 16; m <<= 1)
    #pragma unroll
    for (int rt = 0; rt < 2; ++rt)
      #pragma unroll
      for (int e = 0; e < 16; ++e) {
        gmin[rt][e] = fminf(gmin[rt][e], __shfl_xor(gmin[rt][e], m, 64));
        gmax[rt][e] = fmaxf(gmax[rt][e], __shfl_xor(gmax[rt][e], m, 64));
      }

  if (c31 == 0) {  // lanes 0 and 32: each owns 16 rows per row-tile
    #pragma unroll
    for (int rt = 0; rt < 2; ++rt)
      #pragma unroll
      for (int e = 0; e < 16; ++e) {
        const int row = i0 + rt * 32 + (e & 3) + 8 * (e >> 2) + 4 * h;
        // hardest positive: max_same(sq_j - 2dot) = (128 - 2*gmin) - 2048
        atomicMax(&emax[row], fenc(C0 - 2.f * gmin[rt][e] - BIAS));
        // hardest negative: min_diff(sq_j - 2dot) = 128 - 2*gmax
        atomicMin(&emin[row], fenc(C0 - 2.f * gmax[rt][e]));
      }
  }

  // ---- fused finalize: last chunk-block of this rowgroup handles its 256 rows ----
  __syncthreads();
  if (tid == 0) {
    __threadfence();
    flag = (atomicAdd(&rg_done[bx], 1u) == NCHUNK - 1u);
  }
  __syncthreads();
  if (!flag) return;
  __threadfence();

  const int row = bx * RGR + tid;
  float ps = 0.f, pc = 0.f;
  if (conf[row]) {
    const float hi = fdec(atomicMax(&emax[row], 0u));           // identity read
    const float lo = fdec(atomicMin(&emin[row], 0xFFFFFFFFu));  // identity read
    const float ap = sqrtf(fmaxf(sq[row] + hi, 1e-12f));
    const float an = sqrtf(fmaxf(sq[row] + lo, 1e-12f));
    ps = fmaxf(ap - an, 0.f);
    pc = 1.f;
  }
  #pragma unroll
  for (int m = 1; m < 64; m <<= 1) {
    ps += __shfl_xor(ps, m, 64);
    pc += __shfl_xor(pc, m, 64);
  }
  if (lane == 0) { red[0][wave] = ps; red[1][wave] = pc; }
  __syncthreads();
  if (tid == 0) {
    float S = red[0][0] + red[0][1] + red[0][2] + red[0][3];
    float C = red[1][0] + red[1][1] + red[1][2] + red[1][3];
    atomicAdd(Ssum, S);
    atomicAdd(Csum, C);
    __threadfence();
    if (atomicAdd(g_done, 1u) == NRG - 1u) {
      const float St = atomicAdd(Ssum, 0.f);
      const float Ct = atomicAdd(Csum, 0.f);
      out[0] = (Ct > 0.f) ? (St / fmaxf(Ct, 1.f)) : 0.f;
    }
  }
}

extern "C" void kernel_launch(void* const* d_in, const int* in_sizes, int n_in,
                              void* d_out, int out_size, void* d_ws, size_t ws_size,
                              hipStream_t stream) {
  const float* x    = (const float*)d_in[0];
  const float* pred = (const float*)d_in[1];
  const int*   tgt  = (const int*)d_in[2];
  float* out = (float*)d_out;

  char* w = (char*)d_ws;
  const size_t arr_bytes = (size_t)NROWS * K2 * 2;  // 2.36 MiB each (panel layout)
  short*    xa   = (short*)w;
  short*    xbm  = (short*)(w + arr_bytes);
  float*    sq   = (float*)(w + 2 * arr_bytes);
  unsigned* emax = (unsigned*)(w + 2 * arr_bytes + (size_t)NROWS * 4);
  unsigned* emin = (unsigned*)(w + 2 * arr_bytes + (size_t)NROWS * 8);
  int*      conf = (int*)(w + 2 * arr_bytes + (size_t)NROWS * 12);
  unsigned* ctrs = (unsigned*)(w + 2 * arr_bytes + (size_t)NROWS * 16);

  hipLaunchKernelGGL(prep_k, dim3(NROWS / 4), dim3(256), 0, stream,
                     x, tgt, pred, xa, xbm, sq, emax, emin, conf, ctrs);
  hipLaunchKernelGGL(gram_k, dim3(NRG, NCHUNK), dim3(256), 0, stream,
                     xa, xbm, sq, conf, emax, emin, ctrs, out);
}

// Round 10
// 88.840 us; speedup vs baseline: 1.1067x; 1.1067x over previous
//
#include <hip/hip_runtime.h>

#define NROWS 8192
#define DIMX  128              // raw feature dims
#define KB    192              // i8 K: 128 data + 40 one-hot (4/class) + 24 zero pad
#define KSEG  12               // 16B segments per row
#define PTB   24576            // bytes per 128-row panel tile (128*192)
#define NKS   3                // MFMA K-steps of 64
#define NCLS  10
#define GAPV  0.4f
#define DEBIAS 504.03125f      // 2*4*127*127/256 — exact fp32
#define SCL   (-0.0078125f)    // -2/256
#define RGR   256              // rows per block (4 waves x 64 rows)
#define NRG   (NROWS / RGR)        // 32 rowgroups
#define CHUNK 512              // cols per block
#define NCHUNK (NROWS / CHUNK)     // 16 col-chunks
#define SLAB  64               // cols per LDS slab
#define NSLAB (CHUNK / SLAB)       // 8 slabs

typedef __attribute__((ext_vector_type(4))) int i32x4;

// async 16B/lane global->LDS DMA
#define GLOAD_LDS16(g, l)                                              \
  __builtin_amdgcn_global_load_lds(                                    \
      (const __attribute__((address_space(1))) void*)(g),              \
      (__attribute__((address_space(3))) void*)(l), 16, 0, 0)

// monotone float <-> uint encoding so atomicMax/atomicMin on uint order like floats
__device__ __forceinline__ unsigned fenc(float f) {
  unsigned u = __float_as_uint(f);
  return (u & 0x80000000u) ? ~u : (u | 0x80000000u);
}
__device__ __forceinline__ float fdec(unsigned u) {
  return (u & 0x80000000u) ? __uint_as_float(u & 0x7fffffffu) : __uint_as_float(~u);
}
__device__ __forceinline__ int q8(float v) {  // round-to-nearest int8 of 16*x
  int q = (int)rintf(16.f * v);
  return q > 127 ? 127 : (q < -127 ? -127 : q);
}

// ---- kernel 1: build i8 PANEL arrays (K=192), sq, init accum, confusion, ctrs ----
// panel byte addr = (row>>7)*PTB + kseg*2048 + (row&127)*16 + (byte&15)
// row content: [q8(16x)[0..127], A:+127/B:-127 on dims 128+4c..131+4c for c=cls, 0 pad]
// => D = q_a . q_b = 256*dot_approx - 64516*[same]
//    cand = sq_j - (2/256)*D = sq_j - 2dot + 504.03125*[same]
__global__ __launch_bounds__(256) void prep_k(const float* __restrict__ x,
                                              const int* __restrict__ tgt,
                                              const float* __restrict__ pred,
                                              char* __restrict__ xa,
                                              char* __restrict__ xbm,
                                              float* __restrict__ sq,
                                              unsigned* __restrict__ emax,
                                              unsigned* __restrict__ emin,
                                              int* __restrict__ conf,
                                              unsigned* __restrict__ ctrs) {
  if (blockIdx.x == 0 && threadIdx.x < NRG + 3) ctrs[threadIdx.x] = 0u;

  const int wave = threadIdx.x >> 6;
  const int lane = threadIdx.x & 63;
  const int row  = blockIdx.x * 4 + wave;
  const float2 f2 = ((const float2*)(x + (size_t)row * DIMX))[lane];
  float s = f2.x * f2.x + f2.y * f2.y;
  #pragma unroll
  for (int m = 1; m < 64; m <<= 1) s += __shfl_xor(s, m, 64);

  char* basea = xa  + (size_t)(row >> 7) * PTB + (size_t)(row & 127) * 16;
  char* baseb = xbm + (size_t)(row >> 7) * PTB + (size_t)(row & 127) * 16;
  {  // data elems e=2L,2L+1 -> kseg = L>>3, byte (L&7)*2
    const int q0 = q8(f2.x), q1 = q8(f2.y);
    const unsigned short u = (unsigned short)((q0 & 0xFF) | ((q1 & 0xFF) << 8));
    const size_t off = (size_t)(lane >> 3) * 2048 + (lane & 7) * 2;
    *(unsigned short*)(basea + off) = u;
    *(unsigned short*)(baseb + off) = u;
  }
  const int cls = tgt[row];
  if (lane < 32) {  // aug elems e = 128 + j, j = 2*lane, 2*lane+1
    const int j = 2 * lane;
    const int c = j >> 2;                  // class block (4 dims each)
    const bool hit = (c < NCLS) && (c == cls);
    const unsigned short ua = hit ? (unsigned short)0x7F7F : 0;  // +127,+127
    const unsigned short ub = hit ? (unsigned short)0x8181 : 0;  // -127,-127
    const size_t off = (size_t)(8 + (j >> 4)) * 2048 + (j & 15);
    *(unsigned short*)(basea + off) = ua;
    *(unsigned short*)(baseb + off) = ub;
  }

  if (lane == 0) {
    sq[row]   = s;
    emax[row] = fenc(-INFINITY);
    emin[row] = fenc(INFINITY);
    const float* pp = pred + (size_t)row * NCLS;
    float v[NCLS];
    #pragma unroll
    for (int c = 0; c < NCLS; ++c) v[c] = pp[c];
    float m1 = v[0]; int i1 = 0;
    #pragma unroll
    for (int c = 1; c < NCLS; ++c)
      if (v[c] > m1) { m1 = v[c]; i1 = c; }
    float m2 = -INFINITY, sum = 0.f;
    #pragma unroll
    for (int c = 0; c < NCLS; ++c) {
      sum += __expf(v[c] - m1);
      if (c != i1) m2 = fmaxf(m2, v[c]);
    }
    const float d01 = (1.f - __expf(m2 - m1)) / sum;
    conf[row] = (d01 <= GAPV) || (i1 != cls);
  }
}

// ---- kernel 2: Gram + hard mining, i8 16x16x64 MFMA, DMA-staged B+sq, fused finalize ----
// 4 waves/block x 64 rows (4 x 16-row tiles, A register-resident, 48 VGPRs).
// B: 512-col chunk in 8 x 64-col slabs via global_load_lds; sq slab co-staged.
// Frag: m|n = lane&15, k = quad*16 + byte.  C/D: col=lane&15, row=quad*4+reg.
__global__ __launch_bounds__(256, 2) void gram_k(const char* __restrict__ xa,
                                                 const char* __restrict__ xbm,
                                                 const float* __restrict__ sq,
                                                 const int* __restrict__ conf,
                                                 unsigned* __restrict__ emax,
                                                 unsigned* __restrict__ emin,
                                                 unsigned* __restrict__ ctrs,
                                                 float* __restrict__ out) {
  __shared__ char  ldsb[2][KSEG * 1024];   // per buf: 12 ksegs x 64 cols x 16B = 12 KB
  __shared__ float sqb[2][SLAB];
  __shared__ float red[2][4];
  __shared__ int   flag;
  const int tid  = threadIdx.x;
  const int wave = tid >> 6;
  const int lane = tid & 63;
  const int quad = lane >> 4;   // 0..3
  const int m16  = lane & 15;   // 0..15
  const int bx = blockIdx.x, by = blockIdx.y;
  const int i0 = bx * RGR + wave * 64;

  unsigned* rg_done = ctrs;                 // [NRG]
  unsigned* g_done  = ctrs + NRG;
  float*    Ssum    = (float*)(ctrs + NRG + 1);
  float*    Csum    = (float*)(ctrs + NRG + 2);

  // A fragments: rows i0 + rt*16 + m16, kseg = ks*4 + quad
  i32x4 A[4][NKS];
  #pragma unroll
  for (int rt = 0; rt < 4; ++rt) {
    const int rbase = wave * 64 + rt * 16;               // 0..240 within block rows
    const char* pa = xa + (size_t)(bx * 2 + (rbase >> 7)) * PTB
                        + (size_t)((rbase & 127) + m16) * 16;
    #pragma unroll
    for (int ks = 0; ks < NKS; ++ks)
      A[rt][ks] = *(const i32x4*)(pa + (size_t)(ks * 4 + quad) * 2048);
  }
  #pragma unroll
  for (int rt = 0; rt < 4; ++rt)
    #pragma unroll
    for (int ks = 0; ks < NKS; ++ks)
      asm("" : "+v"(A[rt][ks]));   // keep A resident

  float gmin[4][4], gmax[4][4];
  #pragma unroll
  for (int r = 0; r < 4; ++r)
    #pragma unroll
    for (int q = 0; q < 4; ++q) { gmin[r][q] = INFINITY; gmax[r][q] = -INFINITY; }

  // DMA slab 0: wave w stages ksegs 3w..3w+2; wave 3 lanes<16 also stage sq (64 floats)
  {
    const char* srcb = xbm + (size_t)(by * 4) * PTB;
    #pragma unroll
    for (int u = 0; u < 3; ++u) {
      const int kseg = wave * 3 + u;
      GLOAD_LDS16(srcb + (size_t)kseg * 2048 + lane * 16, &ldsb[0][kseg * 1024 + lane * 16]);
    }
    if (wave == 3 && lane < 16)
      GLOAD_LDS16((const char*)(sq + by * CHUNK) + lane * 16, (char*)&sqb[0][0] + lane * 16);
  }

  for (int s = 0; s < NSLAB; ++s) {
    __syncthreads();   // drains this wave's DMA + syncs buf ready
    if (s + 1 < NSLAB) {
      const char* srcb = xbm + (size_t)(by * 4 + ((s + 1) >> 1)) * PTB + ((s + 1) & 1) * 1024;
      char* dstb = &ldsb[(s + 1) & 1][0];
      #pragma unroll
      for (int u = 0; u < 3; ++u) {
        const int kseg = wave * 3 + u;
        GLOAD_LDS16(srcb + (size_t)kseg * 2048 + lane * 16, dstb + kseg * 1024 + lane * 16);
      }
      if (wave == 3 && lane < 16)
        GLOAD_LDS16((const char*)(sq + by * CHUNK + (s + 1) * SLAB) + lane * 16,
                    (char*)&sqb[(s + 1) & 1][0] + lane * 16);
    }
    // compute slab s: 4 j-tiles of 16 cols
    const char* buf = &ldsb[s & 1][0];
    #pragma unroll
    for (int jt = 0; jt < 4; ++jt) {
      i32x4 B[NKS];
      #pragma unroll
      for (int ks = 0; ks < NKS; ++ks)
        B[ks] = *(const i32x4*)(buf + (ks * 4 + quad) * 1024 + (jt * 16 + m16) * 16);
      const float sqj = sqb[s & 1][jt * 16 + m16];

      i32x4 acc[4];
      #pragma unroll
      for (int r = 0; r < 4; ++r) acc[r] = (i32x4){0, 0, 0, 0};
      #pragma unroll
      for (int ks = 0; ks < NKS; ++ks)
        #pragma unroll
        for (int r = 0; r < 4; ++r)
          acc[r] = __builtin_amdgcn_mfma_i32_16x16x64_i8(A[r][ks], B[ks], acc[r], 0, 0, 0);

      #pragma unroll
      for (int r = 0; r < 4; ++r)
        #pragma unroll
        for (int q = 0; q < 4; ++q) {
          const float cand = fmaf((float)acc[r][q], SCL, sqj);  // sq_j - 2dot + 504.03*same
          gmin[r][q] = fminf(gmin[r][q], cand);
          gmax[r][q] = fmaxf(gmax[r][q], cand);
        }
    }
  }

  // reduce over the 16 cols held across m16 lanes (quad bits preserved)
  #pragma unroll
  for (int m = 1; m <= 8; m <<= 1)
    #pragma unroll
    for (int r = 0; r < 4; ++r)
      #pragma unroll
      for (int q = 0; q < 4; ++q) {
        gmin[r][q] = fminf(gmin[r][q], __shfl_xor(gmin[r][q], m, 64));
        gmax[r][q] = fmaxf(gmax[r][q], __shfl_xor(gmax[r][q], m, 64));
      }

  if (m16 == 0) {
    #pragma unroll
    for (int r = 0; r < 4; ++r)
      #pragma unroll
      for (int q = 0; q < 4; ++q) {
        const int row = i0 + r * 16 + quad * 4 + q;
        atomicMax(&emax[row], fenc(gmax[r][q]));  // biased hardest-positive
        atomicMin(&emin[row], fenc(gmin[r][q]));  // hardest-negative
      }
  }

  // ---- fused finalize: last chunk-block of this rowgroup handles its 256 rows ----
  __syncthreads();
  if (tid == 0) {
    __threadfence();
    flag = (atomicAdd(&rg_done[bx], 1u) == NCHUNK - 1u);
  }
  __syncthreads();
  if (!flag) return;
  __threadfence();

  const int row = bx * RGR + tid;
  float ps = 0.f, pc = 0.f;
  if (conf[row]) {
    const float hi = fdec(atomicMax(&emax[row], 0u));           // identity read
    const float lo = fdec(atomicMin(&emin[row], 0xFFFFFFFFu));  // identity read
    const float ap = sqrtf(fmaxf(sq[row] + hi - DEBIAS, 1e-12f));
    const float an = sqrtf(fmaxf(sq[row] + lo, 1e-12f));
    ps = fmaxf(ap - an, 0.f);
    pc = 1.f;
  }
  #pragma unroll
  for (int m = 1; m < 64; m <<= 1) {
    ps += __shfl_xor(ps, m, 64);
    pc += __shfl_xor(pc, m, 64);
  }
  if (lane == 0) { red[0][wave] = ps; red[1][wave] = pc; }
  __syncthreads();
  if (tid == 0) {
    float S = red[0][0] + red[0][1] + red[0][2] + red[0][3];
    float C = red[1][0] + red[1][1] + red[1][2] + red[1][3];
    atomicAdd(Ssum, S);
    atomicAdd(Csum, C);
    __threadfence();
    if (atomicAdd(g_done, 1u) == NRG - 1u) {
      const float St = atomicAdd(Ssum, 0.f);
      const float Ct = atomicAdd(Csum, 0.f);
      out[0] = (Ct > 0.f) ? (St / fmaxf(Ct, 1.f)) : 0.f;
    }
  }
}

extern "C" void kernel_launch(void* const* d_in, const int* in_sizes, int n_in,
                              void* d_out, int out_size, void* d_ws, size_t ws_size,
                              hipStream_t stream) {
  const float* x    = (const float*)d_in[0];
  const float* pred = (const float*)d_in[1];
  const int*   tgt  = (const int*)d_in[2];
  float* out = (float*)d_out;

  char* w = (char*)d_ws;
  const size_t arr_bytes = (size_t)NROWS * KB;  // 1.57 MiB each (i8 panel layout)
  char*     xa   = w;
  char*     xbm  = w + arr_bytes;
  float*    sq   = (float*)(w + 2 * arr_bytes);
  unsigned* emax = (unsigned*)(w + 2 * arr_bytes + (size_t)NROWS * 4);
  unsigned* emin = (unsigned*)(w + 2 * arr_bytes + (size_t)NROWS * 8);
  int*      conf = (int*)(w + 2 * arr_bytes + (size_t)NROWS * 12);
  unsigned* ctrs = (unsigned*)(w + 2 * arr_bytes + (size_t)NROWS * 16);

  hipLaunchKernelGGL(prep_k, dim3(NROWS / 4), dim3(256), 0, stream,
                     x, tgt, pred, xa, xbm, sq, emax, emin, conf, ctrs);
  hipLaunchKernelGGL(gram_k, dim3(NRG, NCHUNK), dim3(256), 0, stream,
                     xa, xbm, sq, conf, emax, emin, ctrs, out);
}

// Round 11
// 84.610 us; speedup vs baseline: 1.1620x; 1.0500x over previous
//
#include <hip/hip_runtime.h>

#define NROWS 8192
#define DIMX  128              // raw feature dims
#define KB    192              // i8 K: 128 data + 40 one-hot (4/class) + 24 zero pad
#define KSEG  12               // 16B segments per row
#define PTB   24576            // bytes per 128-row panel tile (128*192)
#define NKS   3                // MFMA K-steps of 64
#define NCLS  10
#define GAPV  0.4f
#define DEBIAS 504.03125f      // 2*4*127*127/256 — exact fp32
#define SCL   (-0.0078125f)    // -2/256
#define RGR   256              // rows per block (4 waves x 64 rows)
#define NRG   (NROWS / RGR)        // 32 rowgroups
#define CHUNK 512              // cols per block
#define NCHUNK (NROWS / CHUNK)     // 16 col-chunks
#define SLAB  64               // cols per LDS slab
#define NSLAB (CHUNK / SLAB)       // 8 slabs

typedef __attribute__((ext_vector_type(4))) int i32x4;

// async 16B/lane global->LDS DMA
#define GLOAD_LDS16(g, l)                                              \
  __builtin_amdgcn_global_load_lds(                                    \
      (const __attribute__((address_space(1))) void*)(g),              \
      (__attribute__((address_space(3))) void*)(l), 16, 0, 0)

__device__ __forceinline__ int q8(float v) {  // round-to-nearest int8 of 16*x
  int q = (int)rintf(16.f * v);
  return q > 127 ? 127 : (q < -127 ? -127 : q);
}

// ---- kernel 1: build i8 PANEL arrays (K=192), sq, confusion, zero ctrs ----
// panel byte addr = (row>>7)*PTB + kseg*2048 + (row&127)*16 + (byte&15)
// row content: [q8(16x)[0..127], A:+127/B:-127 on dims 128+4c..131+4c for c=cls, 0 pad]
// => D = q_a . q_b = 256*dot_approx - 64516*[same]
//    cand = sq_j + SCL*D = sq_j - 2dot + 504.03125*[same]
__global__ __launch_bounds__(256) void prep_k(const float* __restrict__ x,
                                              const int* __restrict__ tgt,
                                              const float* __restrict__ pred,
                                              char* __restrict__ xa,
                                              char* __restrict__ xbm,
                                              float* __restrict__ sq,
                                              int* __restrict__ conf,
                                              unsigned* __restrict__ ctrs) {
  if (blockIdx.x == 0 && threadIdx.x < 3) ctrs[threadIdx.x] = 0u;  // g_done, Ssum, Csum

  const int wave = threadIdx.x >> 6;
  const int lane = threadIdx.x & 63;
  const int row  = blockIdx.x * 4 + wave;
  const float2 f2 = ((const float2*)(x + (size_t)row * DIMX))[lane];
  float s = f2.x * f2.x + f2.y * f2.y;
  #pragma unroll
  for (int m = 1; m < 64; m <<= 1) s += __shfl_xor(s, m, 64);

  char* basea = xa  + (size_t)(row >> 7) * PTB + (size_t)(row & 127) * 16;
  char* baseb = xbm + (size_t)(row >> 7) * PTB + (size_t)(row & 127) * 16;
  {  // data elems e=2L,2L+1 -> kseg = L>>3, byte (L&7)*2
    const int q0 = q8(f2.x), q1 = q8(f2.y);
    const unsigned short u = (unsigned short)((q0 & 0xFF) | ((q1 & 0xFF) << 8));
    const size_t off = (size_t)(lane >> 3) * 2048 + (lane & 7) * 2;
    *(unsigned short*)(basea + off) = u;
    *(unsigned short*)(baseb + off) = u;
  }
  const int cls = tgt[row];
  if (lane < 32) {  // aug elems e = 128 + j, j = 2*lane, 2*lane+1
    const int j = 2 * lane;
    const int c = j >> 2;                  // class block (4 dims each)
    const bool hit = (c < NCLS) && (c == cls);
    const unsigned short ua = hit ? (unsigned short)0x7F7F : 0;  // +127,+127
    const unsigned short ub = hit ? (unsigned short)0x8181 : 0;  // -127,-127
    const size_t off = (size_t)(8 + (j >> 4)) * 2048 + (j & 15);
    *(unsigned short*)(basea + off) = ua;
    *(unsigned short*)(baseb + off) = ub;
  }

  if (lane == 0) {
    sq[row] = s;
    const float* pp = pred + (size_t)row * NCLS;
    float v[NCLS];
    #pragma unroll
    for (int c = 0; c < NCLS; ++c) v[c] = pp[c];
    float m1 = v[0]; int i1 = 0;
    #pragma unroll
    for (int c = 1; c < NCLS; ++c)
      if (v[c] > m1) { m1 = v[c]; i1 = c; }
    float m2 = -INFINITY, sum = 0.f;
    #pragma unroll
    for (int c = 0; c < NCLS; ++c) {
      sum += __expf(v[c] - m1);
      if (c != i1) m2 = fmaxf(m2, v[c]);
    }
    const float d01 = (1.f - __expf(m2 - m1)) / sum;
    conf[row] = (d01 <= GAPV) || (i1 != cls);
  }
}

// ---- kernel 2: PURE Gram + hard mining. No atomics, no fences, no finalize. ----
// 4 waves/block x 64 rows (A register-resident). B: 512-col chunk in 8 x 64-col
// slabs via global_load_lds; sq slab co-staged. Epilogue: coalesced float4 stores
// of per-(rowgroup,chunk) min/max slices to a staging buffer.
__global__ __launch_bounds__(256, 2) void gram_k(const char* __restrict__ xa,
                                                 const char* __restrict__ xbm,
                                                 const float* __restrict__ sq,
                                                 float* __restrict__ smax,
                                                 float* __restrict__ smin) {
  __shared__ char  ldsb[2][KSEG * 1024];   // per buf: 12 ksegs x 64 cols x 16B = 12 KB
  __shared__ float sqb[2][SLAB];
  const int tid  = threadIdx.x;
  const int wave = tid >> 6;
  const int lane = tid & 63;
  const int quad = lane >> 4;   // 0..3
  const int m16  = lane & 15;   // 0..15
  const int bx = blockIdx.x, by = blockIdx.y;

  // A fragments: rows bx*256 + wave*64 + rt*16 + m16, kseg = ks*4 + quad
  i32x4 A[4][NKS];
  #pragma unroll
  for (int rt = 0; rt < 4; ++rt) {
    const int rbase = wave * 64 + rt * 16;               // 0..240 within block rows
    const char* pa = xa + (size_t)(bx * 2 + (rbase >> 7)) * PTB
                        + (size_t)((rbase & 127) + m16) * 16;
    #pragma unroll
    for (int ks = 0; ks < NKS; ++ks)
      A[rt][ks] = *(const i32x4*)(pa + (size_t)(ks * 4 + quad) * 2048);
  }
  #pragma unroll
  for (int rt = 0; rt < 4; ++rt)
    #pragma unroll
    for (int ks = 0; ks < NKS; ++ks)
      asm("" : "+v"(A[rt][ks]));   // keep A resident

  float gmin[4][4], gmax[4][4];
  #pragma unroll
  for (int r = 0; r < 4; ++r)
    #pragma unroll
    for (int q = 0; q < 4; ++q) { gmin[r][q] = INFINITY; gmax[r][q] = -INFINITY; }

  // DMA slab 0: wave w stages ksegs 3w..3w+2; wave 3 lanes<16 also stage sq (64 floats)
  {
    const char* srcb = xbm + (size_t)(by * 4) * PTB;
    #pragma unroll
    for (int u = 0; u < 3; ++u) {
      const int kseg = wave * 3 + u;
      GLOAD_LDS16(srcb + (size_t)kseg * 2048 + lane * 16, &ldsb[0][kseg * 1024 + lane * 16]);
    }
    if (wave == 3 && lane < 16)
      GLOAD_LDS16((const char*)(sq + by * CHUNK) + lane * 16, (char*)&sqb[0][0] + lane * 16);
  }

  for (int s = 0; s < NSLAB; ++s) {
    __syncthreads();   // drains this wave's DMA + syncs buf ready
    if (s + 1 < NSLAB) {
      const char* srcb = xbm + (size_t)(by * 4 + ((s + 1) >> 1)) * PTB + ((s + 1) & 1) * 1024;
      char* dstb = &ldsb[(s + 1) & 1][0];
      #pragma unroll
      for (int u = 0; u < 3; ++u) {
        const int kseg = wave * 3 + u;
        GLOAD_LDS16(srcb + (size_t)kseg * 2048 + lane * 16, dstb + kseg * 1024 + lane * 16);
      }
      if (wave == 3 && lane < 16)
        GLOAD_LDS16((const char*)(sq + by * CHUNK + (s + 1) * SLAB) + lane * 16,
                    (char*)&sqb[(s + 1) & 1][0] + lane * 16);
    }
    // compute slab s: 4 j-tiles of 16 cols
    const char* buf = &ldsb[s & 1][0];
    #pragma unroll
    for (int jt = 0; jt < 4; ++jt) {
      i32x4 B[NKS];
      #pragma unroll
      for (int ks = 0; ks < NKS; ++ks)
        B[ks] = *(const i32x4*)(buf + (ks * 4 + quad) * 1024 + (jt * 16 + m16) * 16);
      const float sqj = sqb[s & 1][jt * 16 + m16];

      i32x4 acc[4];
      #pragma unroll
      for (int r = 0; r < 4; ++r) acc[r] = (i32x4){0, 0, 0, 0};
      #pragma unroll
      for (int ks = 0; ks < NKS; ++ks)
        #pragma unroll
        for (int r = 0; r < 4; ++r)
          acc[r] = __builtin_amdgcn_mfma_i32_16x16x64_i8(A[r][ks], B[ks], acc[r], 0, 0, 0);

      #pragma unroll
      for (int r = 0; r < 4; ++r)
        #pragma unroll
        for (int q = 0; q < 4; ++q) {
          const float cand = fmaf((float)acc[r][q], SCL, sqj);  // sq_j - 2dot + 504.03*same
          gmin[r][q] = fminf(gmin[r][q], cand);
          gmax[r][q] = fmaxf(gmax[r][q], cand);
        }
    }
  }

  // reduce over the 16 cols held across m16 lanes (quad bits preserved)
  #pragma unroll
  for (int m = 1; m <= 8; m <<= 1)
    #pragma unroll
    for (int r = 0; r < 4; ++r)
      #pragma unroll
      for (int q = 0; q < 4; ++q) {
        gmin[r][q] = fminf(gmin[r][q], __shfl_xor(gmin[r][q], m, 64));
        gmax[r][q] = fmaxf(gmax[r][q], __shfl_xor(gmax[r][q], m, 64));
      }

  if (m16 == 0) {  // lanes 0/16/32/48: quad q-block of 4 consecutive rows per r-tile
    const size_t sidx = (size_t)(bx * NCHUNK + by) * RGR;
    #pragma unroll
    for (int r = 0; r < 4; ++r) {
      const int lrow = wave * 64 + r * 16 + quad * 4;   // 0..252, multiple of 4
      *(float4*)&smax[sidx + lrow] = make_float4(gmax[r][0], gmax[r][1], gmax[r][2], gmax[r][3]);
      *(float4*)&smin[sidx + lrow] = make_float4(gmin[r][0], gmin[r][1], gmin[r][2], gmin[r][3]);
    }
  }
}

// ---- kernel 3: cross-chunk reduce + loss (32 blocks x 256 threads, 1 row/thread) ----
__global__ __launch_bounds__(256) void reduce_k(const float* __restrict__ smax,
                                                const float* __restrict__ smin,
                                                const float* __restrict__ sq,
                                                const int* __restrict__ conf,
                                                unsigned* __restrict__ ctrs,
                                                float* __restrict__ out) {
  __shared__ float red[2][4];
  const int tid = threadIdx.x, bx = blockIdx.x;
  const int wave = tid >> 6, lane = tid & 63;
  const int row = bx * RGR + tid;

  unsigned* g_done = ctrs;
  float*    Ssum   = (float*)(ctrs + 1);
  float*    Csum   = (float*)(ctrs + 2);

  float hi = -INFINITY, lo = INFINITY;
  #pragma unroll
  for (int c = 0; c < NCHUNK; ++c) {
    hi = fmaxf(hi, smax[(size_t)(bx * NCHUNK + c) * RGR + tid]);
    lo = fminf(lo, smin[(size_t)(bx * NCHUNK + c) * RGR + tid]);
  }
  float ps = 0.f, pc = 0.f;
  if (conf[row]) {
    const float ap = sqrtf(fmaxf(sq[row] + hi - DEBIAS, 1e-12f));  // hardest positive
    const float an = sqrtf(fmaxf(sq[row] + lo, 1e-12f));           // hardest negative
    ps = fmaxf(ap - an, 0.f);
    pc = 1.f;
  }
  #pragma unroll
  for (int m = 1; m < 64; m <<= 1) {
    ps += __shfl_xor(ps, m, 64);
    pc += __shfl_xor(pc, m, 64);
  }
  if (lane == 0) { red[0][wave] = ps; red[1][wave] = pc; }
  __syncthreads();
  if (tid == 0) {
    atomicAdd(Ssum, red[0][0] + red[0][1] + red[0][2] + red[0][3]);
    atomicAdd(Csum, red[1][0] + red[1][1] + red[1][2] + red[1][3]);
    __threadfence();
    if (atomicAdd(g_done, 1u) == NRG - 1u) {
      const float St = atomicAdd(Ssum, 0.f);
      const float Ct = atomicAdd(Csum, 0.f);
      out[0] = (Ct > 0.f) ? (St / fmaxf(Ct, 1.f)) : 0.f;
    }
  }
}

extern "C" void kernel_launch(void* const* d_in, const int* in_sizes, int n_in,
                              void* d_out, int out_size, void* d_ws, size_t ws_size,
                              hipStream_t stream) {
  const float* x    = (const float*)d_in[0];
  const float* pred = (const float*)d_in[1];
  const int*   tgt  = (const int*)d_in[2];
  float* out = (float*)d_out;

  char* w = (char*)d_ws;
  const size_t arr_bytes = (size_t)NROWS * KB;   // 1.57 MiB each (i8 panel layout)
  const size_t stg_bytes = (size_t)NRG * NCHUNK * RGR * 4;  // 512 KiB each
  char*     xa   = w;
  char*     xbm  = w + arr_bytes;
  float*    sq   = (float*)(w + 2 * arr_bytes);
  int*      conf = (int*)(w + 2 * arr_bytes + (size_t)NROWS * 4);
  float*    smax = (float*)(w + 2 * arr_bytes + (size_t)NROWS * 8);
  float*    smin = (float*)(w + 2 * arr_bytes + (size_t)NROWS * 8 + stg_bytes);
  unsigned* ctrs = (unsigned*)(w + 2 * arr_bytes + (size_t)NROWS * 8 + 2 * stg_bytes);

  hipLaunchKernelGGL(prep_k, dim3(NROWS / 4), dim3(256), 0, stream,
                     x, tgt, pred, xa, xbm, sq, conf, ctrs);
  hipLaunchKernelGGL(gram_k, dim3(NRG, NCHUNK), dim3(256), 0, stream,
                     xa, xbm, sq, smax, smin);
  hipLaunchKernelGGL(reduce_k, dim3(NRG), dim3(256), 0, stream,
                     smax, smin, sq, conf, ctrs, out);
}